// Round 5
// baseline (224.592 us; speedup 1.0000x reference)
//
#include <hip/hip_runtime.h>
#include <math.h>

#define BB 128   // batch
#define TT 8     // seq
#define DD 2048  // model dim
#define RR 4     // TT rank
#define VV 512   // vocab

typedef __attribute__((ext_vector_type(8))) short short8;
typedef __attribute__((ext_vector_type(4))) float v4f;

// async global->LDS DMA, 16B per lane; LDS dest = wave-uniform base + lane*16
#define GLL(g, l)                                                              \
    __builtin_amdgcn_global_load_lds(                                          \
        (const __attribute__((address_space(1))) unsigned int*)(g),            \
        (__attribute__((address_space(3))) unsigned int*)(l), 16, 0, 0)

// ---------------- phase A: T-mean -> fmb(bf16), alpha/beta half-partials, zero marg ----------------
__global__ __launch_bounds__(256) void phaseA(const float* __restrict__ inp,
                                              const float* __restrict__ w_alpha,
                                              const float* __restrict__ w_beta,
                                              unsigned short* __restrict__ fmb,
                                              float* __restrict__ alphaP,
                                              float* __restrict__ betaP,
                                              float* __restrict__ marg) {
    int bid = blockIdx.x;
    int b = bid >> 1, half = bid & 1;
    int tid = threadIdx.x;
    if (bid == 0) {
#pragma unroll
        for (int e = 0; e < 8; ++e) marg[e * 256 + tid] = 0.f;
    }
    const float* base = inp + (size_t)b * TT * DD;
    float pa[4] = {0.f, 0.f, 0.f, 0.f};
    float pb[4] = {0.f, 0.f, 0.f, 0.f};
#pragma unroll
    for (int i = 0; i < 4; ++i) {
        int d = half * 1024 + i * 256 + tid;
        float s = 0.f;
#pragma unroll
        for (int t = 0; t < TT; ++t) s += base[t * DD + d];
        float v = s * (1.0f / TT);
        union { float f; unsigned u; } cv; cv.f = v;
        unsigned r = cv.u + 0x7fffu + ((cv.u >> 16) & 1u);   // RNE
        fmb[b * DD + d] = (unsigned short)(r >> 16);
        float4 wa = *(const float4*)(w_alpha + d * 4);
        float4 wb = *(const float4*)(w_beta + d * 4);
        pa[0] += v * wa.x; pa[1] += v * wa.y; pa[2] += v * wa.z; pa[3] += v * wa.w;
        pb[0] += v * wb.x; pb[1] += v * wb.y; pb[2] += v * wb.z; pb[3] += v * wb.w;
    }
#pragma unroll
    for (int r = 0; r < 4; ++r) {
        for (int m = 1; m < 64; m <<= 1) {
            pa[r] += __shfl_xor(pa[r], m);
            pb[r] += __shfl_xor(pb[r], m);
        }
    }
    __shared__ float red[4][8];
    if ((tid & 63) == 0) {
        int w = tid >> 6;
#pragma unroll
        for (int r = 0; r < 4; ++r) { red[w][r] = pa[r]; red[w][4 + r] = pb[r]; }
    }
    __syncthreads();
    if (tid < 8) {
        float s = red[0][tid] + red[1][tid] + red[2][tid] + red[3][tid];
        if (tid < 4) alphaP[(half * BB + b) * 4 + tid] = s;
        else         betaP[(half * BB + b) * 4 + (tid - 4)] = s;
    }
}

// ---------------- phase B: global_load_lds-staged bf16 MFMA GEMM + fused epilogue ----------------
// 512 blocks x 256 thr (2 blocks/CU). Block nb: cols [nb*16, +16), full K=2048 in 16 chunks of 128.
// wv fp32 tile DMA'd into LDS [k][16] (double-buffered, zero VGPR cost); A-frags (L2-hot fmb)
// register-prefetched for chunk c+1 AFTER the DMA issue so no mid-chunk vmcnt wait drains the queue.
__global__ __launch_bounds__(256, 2) void phaseB(const unsigned short* __restrict__ fmb,
                                                 const float* __restrict__ wv,
                                                 const int* __restrict__ labels,
                                                 float* __restrict__ marg,
                                                 float* __restrict__ sel) {
    __shared__ float Wt[2][128][16];   // 16 KB, DMA layout: contiguous [k][c]
    __shared__ int slab[BB * TT];      // 4 KB

    const int tid = threadIdx.x;
    const int nb = blockIdx.x;
    const int col0 = nb * 16;

    slab[tid] = labels[tid];
    slab[tid + 256] = labels[tid + 256];
    slab[tid + 512] = labels[tid + 512];
    slab[tid + 768] = labels[tid + 768];

    const int w = tid >> 6, lane = tid & 63;
    const int m15 = lane & 15, q = lane >> 4;

    // staging addresses: per chunk, round r in {0,1}: 64 rows each; this thread covers
    // row = r*64 + w*16 + lane/4, cols (lane&3)*4 .. +4  (16B, 64B-aligned)
    const int srow = w * 16 + (lane >> 2);
    const float* gsb = wv + (size_t)srow * 8192 + col0 + (lane & 3) * 4;

    // A-frag base: wave w covers rows [w*32, +32) = 2 row-tiles of 16
    const unsigned short* ap = fmb + (size_t)(w * 32 + m15) * DD + q * 8;

    v4f acc[2];
    acc[0] = (v4f){0.f, 0.f, 0.f, 0.f};
    acc[1] = (v4f){0.f, 0.f, 0.f, 0.f};
    short8 afr[2][2][4];   // [buf][tile][ks]

    // ---- prologue: stage chunk 0, A-load chunk 0 ----
    GLL(gsb, &Wt[0][w * 16][0]);
    GLL(gsb + (size_t)64 * 8192, &Wt[0][64 + w * 16][0]);
#pragma unroll
    for (int ks = 0; ks < 4; ++ks) {
        afr[0][0][ks] = *(const short8*)(ap + ks * 32);
        afr[0][1][ks] = *(const short8*)(ap + 16 * DD + ks * 32);
    }
    __syncthreads();

#pragma unroll 1
    for (int c = 0; c < 16; ++c) {
        const int cur = c & 1;
        if (c < 15) {
            // issue next-chunk DMA first (oldest in vmcnt FIFO)
            const float* gs = gsb + (size_t)(c + 1) * 128 * 8192;
            GLL(gs, &Wt[1 - cur][w * 16][0]);
            GLL(gs + (size_t)64 * 8192, &Wt[1 - cur][64 + w * 16][0]);
            // then register-prefetch next-chunk A-frags (consumed only after barrier)
            const unsigned short* an = ap + (c + 1) * 128;
#pragma unroll
            for (int ks = 0; ks < 4; ++ks) {
                afr[1 - cur][0][ks] = *(const short8*)(an + ks * 32);
                afr[1 - cur][1][ks] = *(const short8*)(an + 16 * DD + ks * 32);
            }
        }
        // compute current chunk from LDS (lgkmcnt waits only)
#pragma unroll
        for (int ks = 0; ks < 4; ++ks) {
            float f[8];
#pragma unroll
            for (int j = 0; j < 8; ++j) f[j] = Wt[cur][ks * 32 + q * 8 + j][m15];
            short8 bf;
            unsigned* bu = (unsigned*)&bf;
#pragma unroll
            for (int p = 0; p < 4; ++p) {
                union { float ff; unsigned u; } x0, x1;
                x0.ff = f[2 * p]; x1.ff = f[2 * p + 1];
                bu[p] = (x0.u >> 16) | (x1.u & 0xffff0000u);   // truncate-pack bf16x2
            }
            acc[0] = __builtin_amdgcn_mfma_f32_16x16x32_bf16(afr[cur][0][ks], bf, acc[0], 0, 0, 0);
            acc[1] = __builtin_amdgcn_mfma_f32_16x16x32_bf16(afr[cur][1][ks], bf, acc[1], 0, 0, 0);
        }
        __syncthreads();
    }

    // epilogue: |acc| -> marg atomics + label-select scatter. C layout: row=q*4+r, col=m15.
    const int i4 = (nb >> 7) * 4;                        // i*4
    const int jj = m15 & 3;                              // j
    const int v = (nb & 127) * 4 + (m15 >> 2);           // vocab id of this lane's col
#pragma unroll
    for (int tile = 0; tile < 2; ++tile) {
#pragma unroll
        for (int r = 0; r < 4; ++r) {
            int m = w * 32 + tile * 16 + q * 4 + r;
            float a = fabsf(acc[tile][r]);
            float s = a + __shfl_xor(a, 4);
            s += __shfl_xor(s, 8);
            if (m15 < 4) atomicAdd(&marg[m * 16 + i4 + m15], s);
#pragma unroll
            for (int t = 0; t < TT; ++t) {
                if (slab[m * 8 + t] == v) sel[(m * 8 + t) * 16 + i4 + jj] = a;
            }
        }
    }
}

// ---------------- phase D: chain products, normalizer, loss ----------------
__global__ __launch_bounds__(128) void phaseD(const float* __restrict__ alphaP,
                                              const float* __restrict__ betaP,
                                              const float* __restrict__ marg,
                                              const float* __restrict__ sel,
                                              float* __restrict__ out) {
    int b = threadIdx.x;
    float alpha[4], beta[4];
#pragma unroll
    for (int r = 0; r < 4; ++r) {
        alpha[r] = fabsf(alphaP[b * 4 + r] + alphaP[512 + b * 4 + r]);
        beta[r]  = fabsf(betaP[b * 4 + r] + betaP[512 + b * 4 + r]);
    }
    const float* sb = sel + b * TT * 16;
    float res[16], tmp[16], mm[16], zm[16];
#pragma unroll
    for (int ee = 0; ee < 16; ++ee) res[ee] = sb[ee];
    for (int t = 1; t < TT; ++t) {
        const float* m = sb + t * 16;
#pragma unroll
        for (int i = 0; i < 4; ++i)
#pragma unroll
            for (int jj = 0; jj < 4; ++jj) {
                float s = 0.f;
#pragma unroll
                for (int k = 0; k < 4; ++k) s += res[i * 4 + k] * m[k * 4 + jj];
                tmp[i * 4 + jj] = s;
            }
#pragma unroll
        for (int ee = 0; ee < 16; ++ee) res[ee] = tmp[ee];
    }
#pragma unroll
    for (int ee = 0; ee < 16; ++ee) { mm[ee] = marg[b * 16 + ee]; zm[ee] = mm[ee]; }
    for (int st = 0; st < TT; ++st) {
#pragma unroll
        for (int i = 0; i < 4; ++i)
#pragma unroll
            for (int jj = 0; jj < 4; ++jj) {
                float s = 0.f;
#pragma unroll
                for (int k = 0; k < 4; ++k) s += zm[i * 4 + k] * mm[k * 4 + jj];
                tmp[i * 4 + jj] = s;
            }
#pragma unroll
        for (int ee = 0; ee < 16; ++ee) zm[ee] = tmp[ee];
    }
    float u = 0.f, z = 0.f;
#pragma unroll
    for (int i = 0; i < 4; ++i) {
#pragma unroll
        for (int jj = 0; jj < 4; ++jj) {
            u += alpha[i] * res[i * 4 + jj] * beta[jj];
            z += alpha[i] * zm[i * 4 + jj] * beta[jj];
        }
    }
    float loss = logf(z) - logf(u);
    __shared__ float red[128];
    red[b] = loss;
    __syncthreads();
    for (int off = 64; off >= 1; off >>= 1) {
        if (b < off) red[b] += red[b + off];
        __syncthreads();
    }
    if (b == 0) out[0] = red[0] * (1.0f / BB);
}

extern "C" void kernel_launch(void* const* d_in, const int* in_sizes, int n_in,
                              void* d_out, int out_size, void* d_ws, size_t ws_size,
                              hipStream_t stream) {
    const float* inp     = (const float*)d_in[0];  // [128,8,2048]
    const int*   labels  = (const int*)d_in[1];    // [128,8]
    const float* w_alpha = (const float*)d_in[2];  // [2048,4]
    const float* w_beta  = (const float*)d_in[3];  // [2048,4]
    const float* wv      = (const float*)d_in[4];  // [2048,8192]
    float* out = (float*)d_out;

    float* ws     = (float*)d_ws;
    float* alphaP = ws;                        // [2][128][4]  = 1024
    float* betaP  = ws + 1024;                 // [2][128][4]  = 1024
    float* marg   = ws + 2048;                 // [128][16]    = 2048
    float* sel    = ws + 4096;                 // [128][8][16] = 16384
    unsigned short* fmb = (unsigned short*)(ws + 20480);  // [128][2048] bf16

    phaseA<<<256, 256, 0, stream>>>(inp, w_alpha, w_beta, fmb, alphaP, betaP, marg);
    phaseB<<<512, 256, 0, stream>>>(fmb, wv, labels, marg, sel);
    phaseD<<<1, 128, 0, stream>>>(alphaP, betaP, marg, sel, out);
}

// Round 6
// 145.633 us; speedup vs baseline: 1.5422x; 1.5422x over previous
//
#include <hip/hip_runtime.h>
#include <math.h>

#define BB 128   // batch
#define TT 8     // seq
#define DD 2048  // model dim
#define RR 4     // TT rank
#define VV 512   // vocab

typedef __attribute__((ext_vector_type(8))) short short8;
typedef __attribute__((ext_vector_type(4))) float v4f;

// async global->LDS DMA, 16B per lane; LDS dest = wave-uniform base + lane*16
#define GLL(g, l)                                                              \
    __builtin_amdgcn_global_load_lds(                                          \
        (const __attribute__((address_space(1))) unsigned int*)(g),            \
        (__attribute__((address_space(3))) unsigned int*)(l), 16, 0, 0)

// s_waitcnt imm encoding (gfx9-family): vmcnt[3:0]=bits3:0, expcnt=bits6:4,
// lgkmcnt=bits11:8, vmcnt[5:4]=bits15:14. Wait on vmcnt only:
#define WAIT_VMCNT_10() __builtin_amdgcn_s_waitcnt(0xF7A)   // vmcnt(10)
#define WAIT_VMCNT_0()  __builtin_amdgcn_s_waitcnt(0xF70)   // vmcnt(0)

// ---------------- phase A: T-mean -> fmb(bf16), alpha/beta half-partials, zero marg ----------------
__global__ __launch_bounds__(256) void phaseA(const float* __restrict__ inp,
                                              const float* __restrict__ w_alpha,
                                              const float* __restrict__ w_beta,
                                              unsigned short* __restrict__ fmb,
                                              float* __restrict__ alphaP,
                                              float* __restrict__ betaP,
                                              float* __restrict__ marg) {
    int bid = blockIdx.x;
    int b = bid >> 1, half = bid & 1;
    int tid = threadIdx.x;
    if (bid == 0) {
#pragma unroll
        for (int e = 0; e < 8; ++e) marg[e * 256 + tid] = 0.f;
    }
    const float* base = inp + (size_t)b * TT * DD;
    float pa[4] = {0.f, 0.f, 0.f, 0.f};
    float pb[4] = {0.f, 0.f, 0.f, 0.f};
#pragma unroll
    for (int i = 0; i < 4; ++i) {
        int d = half * 1024 + i * 256 + tid;
        float s = 0.f;
#pragma unroll
        for (int t = 0; t < TT; ++t) s += base[t * DD + d];
        float v = s * (1.0f / TT);
        union { float f; unsigned u; } cv; cv.f = v;
        unsigned r = cv.u + 0x7fffu + ((cv.u >> 16) & 1u);   // RNE
        fmb[b * DD + d] = (unsigned short)(r >> 16);
        float4 wa = *(const float4*)(w_alpha + d * 4);
        float4 wb = *(const float4*)(w_beta + d * 4);
        pa[0] += v * wa.x; pa[1] += v * wa.y; pa[2] += v * wa.z; pa[3] += v * wa.w;
        pb[0] += v * wb.x; pb[1] += v * wb.y; pb[2] += v * wb.z; pb[3] += v * wb.w;
    }
#pragma unroll
    for (int r = 0; r < 4; ++r) {
        for (int m = 1; m < 64; m <<= 1) {
            pa[r] += __shfl_xor(pa[r], m);
            pb[r] += __shfl_xor(pb[r], m);
        }
    }
    __shared__ float red[4][8];
    if ((tid & 63) == 0) {
        int w = tid >> 6;
#pragma unroll
        for (int r = 0; r < 4; ++r) { red[w][r] = pa[r]; red[w][4 + r] = pb[r]; }
    }
    __syncthreads();
    if (tid < 8) {
        float s = red[0][tid] + red[1][tid] + red[2][tid] + red[3][tid];
        if (tid < 4) alphaP[(half * BB + b) * 4 + tid] = s;
        else         betaP[(half * BB + b) * 4 + (tid - 4)] = s;
    }
}

// ---------------- phase B: wave-private DMA staging, barrier-free K-loop ----------------
// 512 blocks x 256 thr (2 blocks/CU, 8 waves/CU). Block = col-group cg (16 cols) x 4 K-quarter
// waves. Wave w: all 128 rows (8 tiles), K range [w*512, +512) in 16 chunks of 32 (1 MFMA K each).
// Per chunk: 2x GLL (16 cols x 32 k fp32 = 2 KB) into wave-private LDS double-buffer; manual
// s_waitcnt vmcnt(10) instead of any barrier. K-quarters combined pre-abs via LDS exchange.
__global__ __launch_bounds__(256, 2) void phaseB(const unsigned short* __restrict__ fmb,
                                                 const float* __restrict__ wv,
                                                 const int* __restrict__ labels,
                                                 float* __restrict__ marg,
                                                 float* __restrict__ sel) {
    __shared__ __align__(16) char lds_raw[36864];
    float* Wt = (float*)lds_raw;                  // staging: wave w buf b at w*1024 + b*512 floats
    float* xch = (float*)lds_raw;                 // overlay after K-loop: [kh][tile][lane] v4f = 32 KB
    int* slab = (int*)(lds_raw + 32768);          // labels, 4 KB

    const int tid = threadIdx.x;
    const int cg = blockIdx.x;                    // [0,512): col-group of 16
    const int col0 = cg * 16;
    const int w = tid >> 6, lane = tid & 63;
    const int m15 = lane & 15, q = lane >> 4;
    const int k0 = w * 512;                       // this wave's K-quarter

    slab[tid] = labels[tid];
    slab[tid + 256] = labels[tid + 256];
    slab[tid + 512] = labels[tid + 512];
    slab[tid + 768] = labels[tid + 768];

    // staging: GLL instr h covers k in [16h,16h+16): lane L -> k = 16h + L/4, cols (L&3)*4..+4
    const float* gs = wv + (size_t)(k0 + (lane >> 2)) * 8192 + col0 + (lane & 3) * 4;
    float* ldsb = Wt + w * 1024;                  // buf0; buf1 at +512 floats

    // A-frag base: tile t rows t*16+m15; chunk c at k0 + c*32 + q*8
    const unsigned short* ap = fmb + (size_t)m15 * DD + k0 + q * 8;

    v4f acc[8];
#pragma unroll
    for (int t = 0; t < 8; ++t) acc[t] = (v4f){0.f, 0.f, 0.f, 0.f};
    short8 afA[8], afB[8];

    // prologue: stage + A-load chunk 0
    GLL(gs, ldsb);
    GLL(gs + (size_t)16 * 8192, ldsb + 256);
#pragma unroll
    for (int t = 0; t < 8; ++t) afA[t] = *(const short8*)(ap + (size_t)t * 16 * DD);

#pragma unroll 1
    for (int cc = 0; cc < 16; cc += 2) {
        // ---- phase even: chunk cc from buf0/afA; prefetch cc+1 into buf1/afB ----
        {
            const int c = cc;                      // c <= 14, so c+1 always valid
            const float* g2 = gs + (size_t)(c + 1) * 32 * 8192;
            GLL(g2, ldsb + 512);
            GLL(g2 + (size_t)16 * 8192, ldsb + 512 + 256);
            const unsigned short* an = ap + (c + 1) * 32;
#pragma unroll
            for (int t = 0; t < 8; ++t) afB[t] = *(const short8*)(an + (size_t)t * 16 * DD);
            WAIT_VMCNT_10();
            float f[8];
#pragma unroll
            for (int j = 0; j < 8; ++j) f[j] = ldsb[(q * 8 + j) * 16 + m15];
            short8 bf;
            unsigned* bu = (unsigned*)&bf;
#pragma unroll
            for (int p = 0; p < 4; ++p) {
                union { float ff; unsigned u; } x0, x1;
                x0.ff = f[2 * p]; x1.ff = f[2 * p + 1];
                bu[p] = (x0.u >> 16) | (x1.u & 0xffff0000u);
            }
#pragma unroll
            for (int t = 0; t < 8; ++t)
                acc[t] = __builtin_amdgcn_mfma_f32_16x16x32_bf16(afA[t], bf, acc[t], 0, 0, 0);
        }
        // ---- phase odd: chunk cc+1 from buf1/afB; prefetch cc+2 into buf0/afA ----
        {
            const int c = cc + 1;
            if (c < 15) {
                const float* g2 = gs + (size_t)(c + 1) * 32 * 8192;
                GLL(g2, ldsb);
                GLL(g2 + (size_t)16 * 8192, ldsb + 256);
                const unsigned short* an = ap + (c + 1) * 32;
#pragma unroll
                for (int t = 0; t < 8; ++t) afA[t] = *(const short8*)(an + (size_t)t * 16 * DD);
                WAIT_VMCNT_10();
            } else {
                WAIT_VMCNT_0();
            }
            float f[8];
#pragma unroll
            for (int j = 0; j < 8; ++j) f[j] = ldsb[512 + (q * 8 + j) * 16 + m15];
            short8 bf;
            unsigned* bu = (unsigned*)&bf;
#pragma unroll
            for (int p = 0; p < 4; ++p) {
                union { float ff; unsigned u; } x0, x1;
                x0.ff = f[2 * p]; x1.ff = f[2 * p + 1];
                bu[p] = (x0.u >> 16) | (x1.u & 0xffff0000u);
            }
#pragma unroll
            for (int t = 0; t < 8; ++t)
                acc[t] = __builtin_amdgcn_mfma_f32_16x16x32_bf16(afB[t], bf, acc[t], 0, 0, 0);
        }
    }

    // ---- combine K-quarters pre-abs via LDS exchange (staging space is dead now) ----
    __syncthreads();   // all waves done with staging reads before overlay writes
#pragma unroll
    for (int t = 0; t < 8; ++t)
        *(v4f*)&xch[((w * 8 + t) * 64 + lane) * 4] = acc[t];
    __syncthreads();

    // wave w finalizes tiles 2w, 2w+1. C layout: row=q*4+r, col=m15.
    const int i4 = (cg >> 7) * 4;                       // i*4
    const int jj = m15 & 3;                             // j
    const int v = (cg & 127) * 4 + (m15 >> 2);          // vocab id of this lane's col
#pragma unroll
    for (int tt = 0; tt < 2; ++tt) {
        const int t = w * 2 + tt;
        v4f s4 = *(const v4f*)&xch[((0 * 8 + t) * 64 + lane) * 4];
        s4 += *(const v4f*)&xch[((1 * 8 + t) * 64 + lane) * 4];
        s4 += *(const v4f*)&xch[((2 * 8 + t) * 64 + lane) * 4];
        s4 += *(const v4f*)&xch[((3 * 8 + t) * 64 + lane) * 4];
#pragma unroll
        for (int r = 0; r < 4; ++r) {
            int m = t * 16 + q * 4 + r;
            float a = fabsf(s4[r]);
            float s = a + __shfl_xor(a, 4);
            s += __shfl_xor(s, 8);
            if (m15 < 4) atomicAdd(&marg[m * 16 + i4 + m15], s);
#pragma unroll
            for (int tL = 0; tL < TT; ++tL) {
                if (slab[m * 8 + tL] == v) sel[(m * 8 + tL) * 16 + i4 + jj] = a;
            }
        }
    }
}

// ---------------- phase D: chain products, normalizer, loss ----------------
__global__ __launch_bounds__(128) void phaseD(const float* __restrict__ alphaP,
                                              const float* __restrict__ betaP,
                                              const float* __restrict__ marg,
                                              const float* __restrict__ sel,
                                              float* __restrict__ out) {
    int b = threadIdx.x;
    float alpha[4], beta[4];
#pragma unroll
    for (int r = 0; r < 4; ++r) {
        alpha[r] = fabsf(alphaP[b * 4 + r] + alphaP[512 + b * 4 + r]);
        beta[r]  = fabsf(betaP[b * 4 + r] + betaP[512 + b * 4 + r]);
    }
    const float* sb = sel + b * TT * 16;
    float res[16], tmp[16], mm[16], zm[16];
#pragma unroll
    for (int ee = 0; ee < 16; ++ee) res[ee] = sb[ee];
    for (int t = 1; t < TT; ++t) {
        const float* m = sb + t * 16;
#pragma unroll
        for (int i = 0; i < 4; ++i)
#pragma unroll
            for (int jj = 0; jj < 4; ++jj) {
                float s = 0.f;
#pragma unroll
                for (int k = 0; k < 4; ++k) s += res[i * 4 + k] * m[k * 4 + jj];
                tmp[i * 4 + jj] = s;
            }
#pragma unroll
        for (int ee = 0; ee < 16; ++ee) res[ee] = tmp[ee];
    }
#pragma unroll
    for (int ee = 0; ee < 16; ++ee) { mm[ee] = marg[b * 16 + ee]; zm[ee] = mm[ee]; }
    for (int st = 0; st < TT; ++st) {
#pragma unroll
        for (int i = 0; i < 4; ++i)
#pragma unroll
            for (int jj = 0; jj < 4; ++jj) {
                float s = 0.f;
#pragma unroll
                for (int k = 0; k < 4; ++k) s += zm[i * 4 + k] * mm[k * 4 + jj];
                tmp[i * 4 + jj] = s;
            }
#pragma unroll
        for (int ee = 0; ee < 16; ++ee) zm[ee] = tmp[ee];
    }
    float u = 0.f, z = 0.f;
#pragma unroll
    for (int i = 0; i < 4; ++i) {
#pragma unroll
        for (int jj = 0; jj < 4; ++jj) {
            u += alpha[i] * res[i * 4 + jj] * beta[jj];
            z += alpha[i] * zm[i * 4 + jj] * beta[jj];
        }
    }
    float loss = logf(z) - logf(u);
    __shared__ float red[128];
    red[b] = loss;
    __syncthreads();
    for (int off = 64; off >= 1; off >>= 1) {
        if (b < off) red[b] += red[b + off];
        __syncthreads();
    }
    if (b == 0) out[0] = red[0] * (1.0f / BB);
}

extern "C" void kernel_launch(void* const* d_in, const int* in_sizes, int n_in,
                              void* d_out, int out_size, void* d_ws, size_t ws_size,
                              hipStream_t stream) {
    const float* inp     = (const float*)d_in[0];  // [128,8,2048]
    const int*   labels  = (const int*)d_in[1];    // [128,8]
    const float* w_alpha = (const float*)d_in[2];  // [2048,4]
    const float* w_beta  = (const float*)d_in[3];  // [2048,4]
    const float* wv      = (const float*)d_in[4];  // [2048,8192]
    float* out = (float*)d_out;

    float* ws     = (float*)d_ws;
    float* alphaP = ws;                        // [2][128][4]  = 1024
    float* betaP  = ws + 1024;                 // [2][128][4]  = 1024
    float* marg   = ws + 2048;                 // [128][16]    = 2048
    float* sel    = ws + 4096;                 // [128][8][16] = 16384
    unsigned short* fmb = (unsigned short*)(ws + 20480);  // [128][2048] bf16

    phaseA<<<256, 256, 0, stream>>>(inp, w_alpha, w_beta, fmb, alphaP, betaP, marg);
    phaseB<<<512, 256, 0, stream>>>(fmb, wv, labels, marg, sel);
    phaseD<<<1, 128, 0, stream>>>(alphaP, betaP, marg, sel, out);
}